// Round 5
// baseline (4070.982 us; speedup 1.0000x reference)
//
#include <hip/hip_runtime.h>

#define B_ 32
#define C_ 8
#define K_ 32
#define M_ 128
#define SXc 17    // RHS row stride (float2)
#define SPc 130   // panel column stride (float2), col-major panels

__device__ __forceinline__ float2 cmul(float2 a, float2 b) {
  return make_float2(a.x*b.x - a.y*b.y, a.x*b.y + a.y*b.x);
}
__device__ __forceinline__ float2 cmulc(float2 a, float2 b) { // a * conj(b)
  return make_float2(a.x*b.x + a.y*b.y, a.y*b.x - a.x*b.y);
}
__device__ __forceinline__ float2 cadd(float2 a, float2 b){ return make_float2(a.x+b.x, a.y+b.y); }
__device__ __forceinline__ float2 csub(float2 a, float2 b){ return make_float2(a.x-b.x, a.y-b.y); }

__device__ void herm4_inv(float2 a[4][4], float2 out[4][4]) {
  float idg[4];
  for (int j = 0; j < 4; ++j) {
    float d = sqrtf(fmaxf(a[j][j].x, 1e-30f));
    float id = 1.f / d;
    idg[j] = id;
    a[j][j] = make_float2(d, 0.f);
    for (int r = j+1; r < 4; ++r) { a[r][j].x *= id; a[r][j].y *= id; }
    for (int c = j+1; c < 4; ++c)
      for (int r = c; r < 4; ++r)
        a[r][c] = csub(a[r][c], cmulc(a[r][j], a[c][j]));
  }
  float2 li[4][4];
  for (int j = 0; j < 4; ++j) {
    li[j][j] = make_float2(idg[j], 0.f);
    for (int r = j+1; r < 4; ++r) {
      float2 s = make_float2(0.f, 0.f);
      for (int d = j; d < r; ++d) s = cadd(s, cmul(a[r][d], li[d][j]));
      li[r][j] = make_float2(-s.x*idg[r], -s.y*idg[r]);
    }
  }
  for (int p = 0; p < 4; ++p)
    for (int q = 0; q < 4; ++q) {
      float2 s = make_float2(0.f, 0.f);
      for (int d = (p > q ? p : q); d < 4; ++d)
        s = cadd(s, cmulc(li[d][q], li[d][p]));
      out[p][q] = s;
    }
}

// 512 threads; thread tile: rows r0=8*(t>>5), cols c0=4*(t&31). ul/Aw register-resident.
// Cholesky: per 16-col panel -> dump to LDS (col-major), wave0 micro-chol + explicit
// inv(L11) stored per-panel in iLs (reused by all solves), parallel TRMM, register
// trailing update. Solves: parallel 16x16 matmuls with iLs + panel updates.
__global__ __launch_bounds__(512, 2) void k_fused(
    const float* __restrict__ v_re, const float* __restrict__ v_im,
    const float* __restrict__ H_re, const float* __restrict__ H_im,
    const float* __restrict__ noise_pow, const float* __restrict__ rweights,
    const float* __restrict__ bss_pow, const int* __restrict__ assign_g,
    void* __restrict__ outp, int omode)
{
  const int t = threadIdx.x;
  const int lane = t & 63, wid = t >> 6;
  const int blk = blockIdx.x;
  const int b = blk >> 3, c = blk & 7;
  const int tm = t >> 5, tp = t & 31;
  const int r0 = tm*8, c0 = tp*4;
  float2* outc = (float2*)outp;

  __shared__ __align__(16) float2 S1[2080];   // Ps (16x130) / phaseA Vs,Tb,covS / Hs+Ys
  __shared__ __align__(16) float2 S2[2176];   // Qs (16x130) / Xs (128x17) / HdVS
  __shared__ __align__(16) float2 iLs[2048];  // 8 panels x 16x16 inv(L11); [pb*256 + d*16 + cc] = iL[cc][d]
  __shared__ __align__(16) float2 uwS[512];
  __shared__ __align__(16) float2 Wall[512];
  __shared__ float invd[16];
  __shared__ float red[8];
  __shared__ int asg[K_], ulist[K_], nc_s;

  float2* Vs   = S1;            // 128 x stride6 (768)
  float2* Tb   = S1 + 768;      // 512
  float2* covS = S1 + 1280;     // 512
  float2* HdVS = S2;            // 512
  float2* Ps   = S1;            // 16 x 130
  float2* Qs   = S2;            // 16 x 130
  float2* Xs   = S2;            // 128 x 17
  float2* Hs   = S1;            // 4 x 130
  float2* Ys   = S1 + 520;      // 4 x 130

  if (t < K_) asg[t] = assign_g[t];
  if (t == 0) {
    int nc = 0;
    for (int k = 0; k < K_; ++k) if (assign_g[k] == c) ulist[nc++] = k;
    nc_s = nc;
  }
  {  // cov := noise * I
    const int k = t >> 4, n = (t >> 2) & 3, q = t & 3;
    covS[t] = make_float2((n == q) ? noise_pow[b*K_ + k] : 0.f, 0.f);
  }
  __syncthreads();
  const int nc = nc_s;
  if (nc == 0) return;

  // ================= phase A: T_{jk} = H[asg_j,k] @ V_j ; cov_k += T T^H =================
  {
    const int pn = t >> 2, qt = t & 3;          // pair (k,n), m-quarter
    const int kk = pn >> 2, nn = pn & 3;
    for (int j = 0; j < K_; ++j) {
      const int vb = (b*K_ + j) * 512;
      Vs[(t >> 2)*6 + (t & 3)] = make_float2(v_re[vb + t], v_im[vb + t]);
      __syncthreads();
      const int hb = ((asg[j]*K_ + kk)*4 + nn) * 128;
      float2 a0 = {0,0}, a1 = {0,0}, a2 = {0,0}, a3 = {0,0};
      for (int m4 = qt*32; m4 < qt*32 + 32; m4 += 4) {
        const float4 hre = *(const float4*)&H_re[hb + m4];
        const float4 him = *(const float4*)&H_im[hb + m4];
        const float hx[4] = {hre.x, hre.y, hre.z, hre.w};
        const float hy[4] = {him.x, him.y, him.z, him.w};
        #pragma unroll
        for (int i = 0; i < 4; ++i) {
          const float4 v01 = *(const float4*)&Vs[(m4 + i)*6];
          const float4 v23 = *(const float4*)&Vs[(m4 + i)*6 + 2];
          a0.x += hx[i]*v01.x - hy[i]*v01.y; a0.y += hx[i]*v01.y + hy[i]*v01.x;
          a1.x += hx[i]*v01.z - hy[i]*v01.w; a1.y += hx[i]*v01.w + hy[i]*v01.z;
          a2.x += hx[i]*v23.x - hy[i]*v23.y; a2.y += hx[i]*v23.y + hy[i]*v23.x;
          a3.x += hx[i]*v23.z - hy[i]*v23.w; a3.y += hx[i]*v23.w + hy[i]*v23.z;
        }
      }
      #pragma unroll
      for (int o = 1; o <= 2; o <<= 1) {      // reduce over qt (lane bits 0..1)
        a0.x += __shfl_xor(a0.x, o, 64); a0.y += __shfl_xor(a0.y, o, 64);
        a1.x += __shfl_xor(a1.x, o, 64); a1.y += __shfl_xor(a1.y, o, 64);
        a2.x += __shfl_xor(a2.x, o, 64); a2.y += __shfl_xor(a2.y, o, 64);
        a3.x += __shfl_xor(a3.x, o, 64); a3.y += __shfl_xor(a3.y, o, 64);
      }
      if (qt == 0) {
        Tb[pn*4 + 0] = a0; Tb[pn*4 + 1] = a1; Tb[pn*4 + 2] = a2; Tb[pn*4 + 3] = a3;
      }
      __syncthreads();
      {
        const int k2 = t >> 4, n2 = (t >> 2) & 3, q2 = t & 3;
        float2 acc = covS[t];
        #pragma unroll
        for (int p = 0; p < 4; ++p)
          acc = cadd(acc, cmulc(Tb[(k2*4 + n2)*4 + p], Tb[(k2*4 + q2)*4 + p]));
        covS[t] = acc;
        if (k2 == j) HdVS[k2*16 + n2*4 + q2] = Tb[(k2*4 + n2)*4 + q2];
      }
      __syncthreads();
    }
  }

  // ================= phase B: per-user 4x4 chain (one thread/user) =================
  if (t < K_) {
    const int k = t;
    float2 a[4][4], ic[4][4], hv[4][4], u[4][4], wi[4][4], w[4][4], uw[4][4], W[4][4];
    const float rwk = rweights[b*K_ + k];
    for (int r = 0; r < 4; ++r)
      for (int c2 = 0; c2 < 4; ++c2) a[r][c2] = covS[k*16 + r*4 + c2];
    herm4_inv(a, ic);
    for (int r = 0; r < 4; ++r)
      for (int c2 = 0; c2 < 4; ++c2) hv[r][c2] = HdVS[k*16 + r*4 + c2];
    for (int n = 0; n < 4; ++n)
      for (int p = 0; p < 4; ++p) {
        float2 s = {0,0};
        for (int q = 0; q < 4; ++q) s = cadd(s, cmul(ic[n][q], hv[q][p]));
        u[n][p] = s;
      }
    for (int n = 0; n < 4; ++n)
      for (int p = 0; p < 4; ++p) {
        float2 s = make_float2((n == p) ? 1.f : 0.f, 0.f);
        for (int q = 0; q < 4; ++q) s = csub(s, cmulc(hv[q][p], u[q][n]));
        wi[n][p] = s;
      }
    herm4_inv(wi, w);
    for (int n = 0; n < 4; ++n)
      for (int q = 0; q < 4; ++q) {
        float2 s = {0,0};
        for (int p = 0; p < 4; ++p) s = cadd(s, cmul(u[n][p], w[p][q]));
        uw[n][q] = s;
      }
    for (int n = 0; n < 4; ++n)
      for (int r = 0; r < 4; ++r) {
        float2 s = {0,0};
        for (int q = 0; q < 4; ++q) s = cadd(s, cmulc(uw[n][q], u[r][q]));
        W[n][r] = make_float2(s.x * rwk, s.y * rwk);
      }
    for (int n = 0; n < 4; ++n)
      for (int r = n; r < 4; ++r) {
        float2 x1 = W[n][r], x2 = W[r][n];
        float2 hm = make_float2(0.5f*(x1.x + x2.x), 0.5f*(x1.y - x2.y));
        W[n][r] = hm; W[r][n] = make_float2(hm.x, -hm.y);
      }
    for (int idx = 0; idx < 16; ++idx) {
      uwS[k*16 + idx]  = uw[idx >> 2][idx & 3];
      Wall[k*16 + idx] = W[idx >> 2][idx & 3];
    }
  }
  __syncthreads();

  // ========== bracket: vt -> d_out (omode0) ; tr(aux) = sum ||vt||^2 ==========
  float tr = 0.f;
  {
    const int m = t >> 2, q = t & 3;
    for (int ui = 0; ui < nc; ++ui) {
      const int k = ulist[ui];
      const float rwk = rweights[b*K_ + k];
      const int hb = (c*K_ + k) * 512;
      float2 acc = {0,0};
      #pragma unroll
      for (int n = 0; n < 4; ++n)
        acc = cadd(acc, cmulc(uwS[k*16 + n*4 + q],
                              make_float2(H_re[hb + n*128 + m], H_im[hb + n*128 + m])));
      acc.x *= rwk; acc.y *= rwk;
      if (omode == 0) outc[(size_t)(b*K_ + k)*512 + t] = acc;
      tr += acc.x*acc.x + acc.y*acc.y;
    }
  }
  #pragma unroll
  for (int o = 32; o >= 1; o >>= 1) tr += __shfl_xor(tr, o, 64);
  if (lane == 0) red[wid] = tr;
  __syncthreads();
  tr = 0.f;
  #pragma unroll
  for (int w8 = 0; w8 < 8; ++w8) tr += red[w8];
  const float inv_bss = 1.f / bss_pow[b*C_ + c];
  float hi = sqrtf(tr * inv_bss);
  float lo = 0.f;

  // ========== ul = sum_k H[c,k]^H W_k H[c,k] into registers (8x4/thread) ==========
  float2 ul[8][4];
  #pragma unroll
  for (int a = 0; a < 8; ++a)
    #pragma unroll
    for (int bb = 0; bb < 4; ++bb) ul[a][bb] = make_float2(0.f, 0.f);
  __syncthreads();
  for (int k = 0; k < K_; ++k) {
    const int hb = (c*K_ + k) * 512;
    Hs[(t >> 7)*130 + (t & 127)] = make_float2(H_re[hb + t], H_im[hb + t]);
    __syncthreads();
    {
      const int n = t >> 7, p = t & 127;
      float2 y = {0,0};
      #pragma unroll
      for (int o = 0; o < 4; ++o) y = cadd(y, cmul(Wall[k*16 + n*4 + o], Hs[o*130 + p]));
      Ys[n*130 + p] = y;
    }
    __syncthreads();
    #pragma unroll
    for (int n = 0; n < 4; ++n) {
      float2 h[8], y[4];
      #pragma unroll
      for (int a2 = 0; a2 < 8; a2 += 2) {
        const float4 h4 = *(const float4*)&Hs[n*130 + r0 + a2];
        h[a2] = make_float2(h4.x, h4.y); h[a2+1] = make_float2(h4.z, h4.w);
      }
      {
        const float4 y0 = *(const float4*)&Ys[n*130 + c0];
        const float4 y1 = *(const float4*)&Ys[n*130 + c0 + 2];
        y[0] = make_float2(y0.x, y0.y); y[1] = make_float2(y0.z, y0.w);
        y[2] = make_float2(y1.x, y1.y); y[3] = make_float2(y1.z, y1.w);
      }
      #pragma unroll
      for (int a = 0; a < 8; ++a)
        #pragma unroll
        for (int bb = 0; bb < 4; ++bb) {   // ul += conj(h)*y
          ul[a][bb].x += h[a].x*y[bb].x + h[a].y*y[bb].y;
          ul[a][bb].y += h[a].x*y[bb].y - h[a].y*y[bb].x;
        }
    }
    __syncthreads();
  }

  // ========== bisection (8 iters) + final solve ==========
  float2 Aw[8][4];
  for (int it = 0; it <= 8; ++it) {
    const float mu = 0.5f*(lo + hi);
    #pragma unroll
    for (int a = 0; a < 8; ++a)
      #pragma unroll
      for (int bb = 0; bb < 4; ++bb) Aw[a][bb] = ul[a][bb];
    if ((tp >> 1) == tm) {
      #pragma unroll
      for (int bb = 0; bb < 4; ++bb) Aw[c0 - r0 + bb][bb].x += mu;
    }
    __syncthreads();

    // ---------------- factor ----------------
    for (int pb = 0; pb < 8; ++pb) {
      const int J = pb * 16;
      if ((tp >> 2) == pb) {              // dump column-panel to Ps
        #pragma unroll
        for (int bb = 0; bb < 4; ++bb)
          #pragma unroll
          for (int a2 = 0; a2 < 8; a2 += 2)
            *(float4*)&Ps[(c0 - J + bb)*SPc + r0 + a2] =
              make_float4(Aw[a2][bb].x, Aw[a2][bb].y, Aw[a2+1][bb].x, Aw[a2+1][bb].y);
      }
      __syncthreads();
      if (wid == 0) {                     // 16x16 micro-cholesky, lane-per-row
        const int r = lane;
        float2 xrow[16];
        #pragma unroll
        for (int d = 0; d < 16; ++d)
          xrow[d] = (r < 16) ? Ps[d*SPc + J + r] : make_float2(0.f, 0.f);
        #pragma unroll
        for (int jj = 0; jj < 16; ++jj) {
          const float piv = __shfl(xrow[jj].x, jj, 64);
          const float dv = sqrtf(fmaxf(piv, 1e-30f));
          const float id = 1.f / dv;
          if (r == jj) { xrow[jj] = make_float2(dv, 0.f); invd[jj] = id; }
          else if (r < 16 && r > jj) { xrow[jj].x *= id; xrow[jj].y *= id; }
          #pragma unroll
          for (int cc = jj + 1; cc < 16; ++cc) {
            float2 lv;
            lv.x = __shfl(xrow[jj].x, cc, 64);
            lv.y = __shfl(xrow[jj].y, cc, 64);
            if (r < 16 && r >= cc) xrow[cc] = csub(xrow[cc], cmulc(xrow[jj], lv));
          }
        }
        if (r < 16) {
          #pragma unroll
          for (int d = 0; d < 16; ++d) Ps[d*SPc + J + r] = xrow[d];
        }
      }
      __syncthreads();
      if (wid == 0 && lane < 16) {        // inv(L11) column-per-lane -> iLs
        const int cc = lane;
        float idr[16];
        #pragma unroll
        for (int d = 0; d < 16; ++d) idr[d] = invd[d];
        float2 x[16];
        #pragma unroll
        for (int d = 0; d < 16; ++d) x[d] = make_float2(0.f, 0.f);
        x[cc] = make_float2(idr[cc], 0.f);
        for (int d = 1; d < 16; ++d) {
          if (d > cc) {
            float2 s = {0,0};
            for (int j2 = cc; j2 < d; ++j2)
              s = cadd(s, cmul(Ps[j2*SPc + J + d], x[j2]));   // L11[d][j2]
            x[d] = make_float2(-s.x*idr[d], -s.y*idr[d]);
          }
        }
        for (int d = cc; d < 16; ++d) iLs[(pb << 8) + (cc << 4) + d] = x[d];  // iL[d][cc]
      }
      __syncthreads();
      const int R = 112 - J;
      for (int idx = t; idx < R*16; idx += 512) {   // TRMM: L21 = A21 * inv(L11)^H -> Qs
        const int rr = J + 16 + (idx >> 4);
        const int cc = idx & 15;
        float2 s = {0,0};
        for (int d = 0; d <= cc; ++d)
          s = cadd(s, cmulc(Ps[d*SPc + rr], iLs[(pb << 8) + (d << 4) + cc]));  // iL[cc][d]
        Qs[cc*SPc + rr] = s;
      }
      __syncthreads();
      if ((tp >> 2) == pb) {              // register write-back of factored panel
        if (r0 >= J + 16) {
          #pragma unroll
          for (int bb = 0; bb < 4; ++bb)
            #pragma unroll
            for (int a = 0; a < 8; ++a) Aw[a][bb] = Qs[(c0 - J + bb)*SPc + r0 + a];
        } else if (r0 >= J) {
          #pragma unroll
          for (int bb = 0; bb < 4; ++bb)
            #pragma unroll
            for (int a = 0; a < 8; ++a) Aw[a][bb] = Ps[(c0 - J + bb)*SPc + r0 + a];
        }
      } else if (tp >= 4*(pb + 1) && r0 + 7 >= c0) {   // trailing: Aw -= Lr * Lc^H
        for (int d = 0; d < 16; ++d) {
          float2 lr[8], lc[4];
          #pragma unroll
          for (int a2 = 0; a2 < 8; a2 += 2) {
            const float4 u0 = *(const float4*)&Qs[d*SPc + r0 + a2];
            lr[a2] = make_float2(u0.x, u0.y); lr[a2+1] = make_float2(u0.z, u0.w);
          }
          {
            const float4 u0 = *(const float4*)&Qs[d*SPc + c0];
            const float4 u1 = *(const float4*)&Qs[d*SPc + c0 + 2];
            lc[0] = make_float2(u0.x, u0.y); lc[1] = make_float2(u0.z, u0.w);
            lc[2] = make_float2(u1.x, u1.y); lc[3] = make_float2(u1.z, u1.w);
          }
          #pragma unroll
          for (int a = 0; a < 8; ++a)
            #pragma unroll
            for (int bb = 0; bb < 4; ++bb) {
              Aw[a][bb].x -= lr[a].x*lc[bb].x + lr[a].y*lc[bb].y;
              Aw[a][bb].y -= lr[a].y*lc[bb].x - lr[a].x*lc[bb].y;
            }
        }
      }
      __syncthreads();
    }

    // ---------------- solves over RHS tiles of 4 users ----------------
    float floc = 0.f;
    for (int t0 = 0; t0 < nc; t0 += 4) {
      for (int s = t; s < 2048; s += 512) {   // stage RHS
        const int m = s >> 4, cl = s & 15, slot = cl >> 2, q = cl & 3;
        float2 v = {0,0};
        if (t0 + slot < nc) {
          const int k = ulist[t0 + slot];
          if (omode == 0) {
            v = outc[(size_t)(b*K_ + k)*512 + m*4 + q];
          } else {
            const int hb = (c*K_ + k) * 512;
            float2 acc = {0,0};
            #pragma unroll
            for (int n = 0; n < 4; ++n)
              acc = cadd(acc, cmulc(uwS[k*16 + n*4 + q],
                                    make_float2(H_re[hb + n*128 + m], H_im[hb + n*128 + m])));
            const float rwk = rweights[b*K_ + k];
            v = make_float2(acc.x*rwk, acc.y*rwk);
          }
        }
        Xs[m*SXc + cl] = v;
      }
      __syncthreads();

      // forward solve: per panel, parallel 16x16 matmul with iLs + panel update
      for (int pb = 0; pb < 8; ++pb) {
        const int J = pb * 16;
        if (pb < 7 && (tp >> 2) == pb) {
          #pragma unroll
          for (int bb = 0; bb < 4; ++bb)
            #pragma unroll
            for (int a2 = 0; a2 < 8; a2 += 2)
              *(float4*)&Ps[(c0 - J + bb)*SPc + r0 + a2] =
                make_float4(Aw[a2][bb].x, Aw[a2][bb].y, Aw[a2+1][bb].x, Aw[a2+1][bb].y);
        }
        float2 yreg = {0,0};
        const int d2 = t >> 4, colx = t & 15;
        if (t < 256) {
          for (int j2 = 0; j2 <= d2; ++j2)
            yreg = cadd(yreg, cmul(iLs[(pb << 8) + (j2 << 4) + d2], Xs[(J + j2)*SXc + colx]));
        }
        __syncthreads();
        if (t < 256) Xs[(J + d2)*SXc + colx] = yreg;
        __syncthreads();
        if (J < 112) {
          const int R = 112 - J;
          for (int idx = t; idx < R*16; idx += 512) {
            const int rr = J + 16 + (idx >> 4), col2 = idx & 15;
            float2 acc = Xs[rr*SXc + col2];
            #pragma unroll
            for (int d = 0; d < 16; ++d)
              acc = csub(acc, cmul(Ps[d*SPc + rr], Xs[(J + d)*SXc + col2]));
            Xs[rr*SXc + col2] = acc;
          }
        }
        __syncthreads();
      }

      // backward solve
      for (int pb = 7; pb >= 0; --pb) {
        const int J = pb * 16;
        if (pb < 7 && (tp >> 2) == pb) {
          #pragma unroll
          for (int bb = 0; bb < 4; ++bb)
            #pragma unroll
            for (int a2 = 0; a2 < 8; a2 += 2)
              *(float4*)&Ps[(c0 - J + bb)*SPc + r0 + a2] =
                make_float4(Aw[a2][bb].x, Aw[a2][bb].y, Aw[a2+1][bb].x, Aw[a2+1][bb].y);
        }
        __syncthreads();
        if (pb < 7 && t < 256) {           // reflect: y'[d] = y[d] - sum_r conj(L[r][J+d]) x[r]
          const int d = t >> 4, col2 = t & 15;
          float2 acc = Xs[(J + d)*SXc + col2];
          for (int rr = J + 16; rr < 128; ++rr)
            acc = csub(acc, cmulc(Xs[rr*SXc + col2], Ps[d*SPc + rr]));
          Xs[(J + d)*SXc + col2] = acc;
        }
        __syncthreads();
        float2 xreg = {0,0};
        const int d3 = t >> 4, colx = t & 15;
        if (t < 256) {                     // x[d] = sum_{j>=d} conj(iL[j][d]) y'[j]
          for (int j2 = d3; j2 < 16; ++j2)
            xreg = cadd(xreg, cmulc(Xs[(J + j2)*SXc + colx], iLs[(pb << 8) + (d3 << 4) + j2]));
        }
        __syncthreads();
        if (t < 256) Xs[(J + d3)*SXc + colx] = xreg;
        __syncthreads();
      }

      if (it < 8) {
        for (int s = t; s < 2048; s += 512) {
          const float2 v = Xs[(s >> 4)*SXc + (s & 15)];
          floc += v.x*v.x + v.y*v.y;
        }
      } else {
        for (int s = t; s < 2048; s += 512) {
          const int m = s >> 4, cl = s & 15, slot = cl >> 2, q = cl & 3;
          if (t0 + slot < nc) {
            const size_t oe = (size_t)(b*K_ + ulist[t0 + slot])*512 + m*4 + q;
            const float2 v = Xs[m*SXc + cl];
            if (omode == 0) ((float2*)outp)[oe] = v;
            else            ((float*)outp)[oe]  = v.x;
          }
        }
      }
      __syncthreads();
    }

    if (it < 8) {
      #pragma unroll
      for (int o = 32; o >= 1; o >>= 1) floc += __shfl_xor(floc, o, 64);
      if (lane == 0) red[wid] = floc;
      __syncthreads();
      float f = 0.f;
      #pragma unroll
      for (int w8 = 0; w8 < 8; ++w8) f += red[w8];
      f *= inv_bss;
      if (f > 1.0f) lo = mu; else hi = mu;
      __syncthreads();
    }
  }
}

// ======================================================================================
extern "C" void kernel_launch(void* const* d_in, const int* in_sizes, int n_in,
                              void* d_out, int out_size, void* d_ws, size_t ws_size,
                              hipStream_t stream)
{
  (void)in_sizes; (void)n_in; (void)d_ws; (void)ws_size;
  const float* v_re   = (const float*)d_in[0];
  const float* v_im   = (const float*)d_in[1];
  const float* H_re   = (const float*)d_in[2];
  const float* H_im   = (const float*)d_in[3];
  const float* noise  = (const float*)d_in[4];
  const float* rw     = (const float*)d_in[5];
  const float* bss    = (const float*)d_in[6];
  const int*   assign = (const int*)d_in[7];

  const int omode = (out_size == B_*K_*M_*4) ? 1 : 0;   // complex-interleaved vs real-only

  hipLaunchKernelGGL(k_fused, dim3(B_*C_), dim3(512), 0, stream,
                     v_re, v_im, H_re, H_im, noise, rw, bss, assign, d_out, omode);
}

// Round 6
// 3755.074 us; speedup vs baseline: 1.0841x; 1.0841x over previous
//
#include <hip/hip_runtime.h>

#define B_ 32
#define C_ 8
#define K_ 32

__device__ __forceinline__ float2 cmul(float2 a, float2 b) {
  return make_float2(a.x*b.x - a.y*b.y, a.x*b.y + a.y*b.x);
}
__device__ __forceinline__ float2 cmulc(float2 a, float2 b) { // a * conj(b)
  return make_float2(a.x*b.x + a.y*b.y, a.y*b.x - a.x*b.y);
}
__device__ __forceinline__ float2 cadd(float2 a, float2 b){ return make_float2(a.x+b.x, a.y+b.y); }
__device__ __forceinline__ float2 csub(float2 a, float2 b){ return make_float2(a.x-b.x, a.y-b.y); }

__device__ void herm4_inv(float2 a[4][4], float2 out[4][4]) {
  float idg[4];
  for (int j = 0; j < 4; ++j) {
    float d = sqrtf(fmaxf(a[j][j].x, 1e-30f));
    float id = 1.f / d;
    idg[j] = id;
    a[j][j] = make_float2(d, 0.f);
    for (int r = j+1; r < 4; ++r) { a[r][j].x *= id; a[r][j].y *= id; }
    for (int c = j+1; c < 4; ++c)
      for (int r = c; r < 4; ++r)
        a[r][c] = csub(a[r][c], cmulc(a[r][j], a[c][j]));
  }
  float2 li[4][4];
  for (int j = 0; j < 4; ++j) {
    li[j][j] = make_float2(idg[j], 0.f);
    for (int r = j+1; r < 4; ++r) {
      float2 s = make_float2(0.f, 0.f);
      for (int d = j; d < r; ++d) s = cadd(s, cmul(a[r][d], li[d][j]));
      li[r][j] = make_float2(-s.x*idg[r], -s.y*idg[r]);
    }
  }
  for (int p = 0; p < 4; ++p)
    for (int q = 0; q < 4; ++q) {
      float2 s = make_float2(0.f, 0.f);
      for (int d = (p > q ? p : q); d < 4; ++d)
        s = cadd(s, cmulc(li[d][q], li[d][p]));
      out[p][q] = s;
    }
}

// One block per (b,c), 512 threads. Thread (tm=t>>5, tp=t&31) owns:
//   A rows 8tm..8tm+7 x cols 4tp..4tp+3 (register-resident 128x128 Hermitian ul,
//   later the Householder vectors), and B rows 8tm.. x cols {tp+32*b4}
//   (RHS v_tilde -> g = Q^H vt -> z -> y = Q z).
// Pipeline: cov/4x4 chain -> vt -> ul -> Householder tridiag (127 steps, B fused)
//           -> bisection via Thomas solves (wave 0, no barriers) -> back-transform.
__global__ __launch_bounds__(512) void k_fused(
    const float* __restrict__ v_re, const float* __restrict__ v_im,
    const float* __restrict__ H_re, const float* __restrict__ H_im,
    const float* __restrict__ noise_pow, const float* __restrict__ rweights,
    const float* __restrict__ bss_pow, const int* __restrict__ assign_g,
    void* __restrict__ outp, int omode)
{
  const int t = threadIdx.x;
  const int lane = t & 63, wid = t >> 6;
  const int blk = blockIdx.x;
  const int b = blk >> 3, c = blk & 7;
  const int tm = t >> 5, tp = t & 31;
  const int rbase = tm * 8;

  __shared__ __align__(16) float2 Arena[4096];  // 32 KB: phaseA arrays | Hs/Ys | Bs
  __shared__ __align__(16) float2 pS[2048];     // 16 KB: Wall/uwS early, dot partials later
  __shared__ __align__(16) float2 vS[128];
  __shared__ __align__(16) float2 wS[128];
  __shared__ __align__(16) float2 colS[128];
  __shared__ __align__(16) float2 pvS[128];
  __shared__ __align__(16) float2 tauS[128];
  __shared__ float dS[128], eS[128], cpS[128];
  __shared__ float red[8];
  __shared__ int asg[K_], ulist[K_], nc_s;

  float2* Wall = pS;              // 512
  float2* uwS  = pS + 512;        // 512
  float2* Vs   = Arena;           // 768 (phase A)
  float2* Tb   = Arena + 768;     // 512
  float2* covS = Arena + 1280;    // 512
  float2* HdVS = Arena + 1792;    // 512
  float2* Hs   = Arena;           // 520 (ul phase)
  float2* Ys   = Arena + 520;     // 520
  float2* Bs   = Arena;           // 4096 (bisection scratch, 128 x 32)

  if (t < K_) asg[t] = assign_g[t];
  if (t == 0) {
    int nc = 0;
    for (int k = 0; k < K_; ++k) if (assign_g[k] == c) ulist[nc++] = k;
    nc_s = nc;
  }
  {  // cov := noise * I
    const int k = t >> 4, n = (t >> 2) & 3, q = t & 3;
    covS[t] = make_float2((n == q) ? noise_pow[b*K_ + k] : 0.f, 0.f);
  }
  __syncthreads();
  const int nc = nc_s;
  if (nc == 0) return;

  // ============ phase A: T_{jk} = H[asg_j,k] @ V_j ; cov_k += T T^H ============
  {
    const int pn = t >> 2, qt = t & 3;
    const int kk = pn >> 2, nn = pn & 3;
    for (int j = 0; j < K_; ++j) {
      const int vb = (b*K_ + j) * 512;
      Vs[(t >> 2)*6 + (t & 3)] = make_float2(v_re[vb + t], v_im[vb + t]);
      __syncthreads();
      const int hb = ((asg[j]*K_ + kk)*4 + nn) * 128;
      float2 a0 = {0,0}, a1 = {0,0}, a2 = {0,0}, a3 = {0,0};
      for (int m4 = qt*32; m4 < qt*32 + 32; m4 += 4) {
        const float4 hre = *(const float4*)&H_re[hb + m4];
        const float4 him = *(const float4*)&H_im[hb + m4];
        const float hx[4] = {hre.x, hre.y, hre.z, hre.w};
        const float hy[4] = {him.x, him.y, him.z, him.w};
        #pragma unroll
        for (int i = 0; i < 4; ++i) {
          const float4 v01 = *(const float4*)&Vs[(m4 + i)*6];
          const float4 v23 = *(const float4*)&Vs[(m4 + i)*6 + 2];
          a0.x += hx[i]*v01.x - hy[i]*v01.y; a0.y += hx[i]*v01.y + hy[i]*v01.x;
          a1.x += hx[i]*v01.z - hy[i]*v01.w; a1.y += hx[i]*v01.w + hy[i]*v01.z;
          a2.x += hx[i]*v23.x - hy[i]*v23.y; a2.y += hx[i]*v23.y + hy[i]*v23.x;
          a3.x += hx[i]*v23.z - hy[i]*v23.w; a3.y += hx[i]*v23.w + hy[i]*v23.z;
        }
      }
      #pragma unroll
      for (int o = 1; o <= 2; o <<= 1) {
        a0.x += __shfl_xor(a0.x, o, 64); a0.y += __shfl_xor(a0.y, o, 64);
        a1.x += __shfl_xor(a1.x, o, 64); a1.y += __shfl_xor(a1.y, o, 64);
        a2.x += __shfl_xor(a2.x, o, 64); a2.y += __shfl_xor(a2.y, o, 64);
        a3.x += __shfl_xor(a3.x, o, 64); a3.y += __shfl_xor(a3.y, o, 64);
      }
      if (qt == 0) {
        Tb[pn*4 + 0] = a0; Tb[pn*4 + 1] = a1; Tb[pn*4 + 2] = a2; Tb[pn*4 + 3] = a3;
      }
      __syncthreads();
      {
        const int k2 = t >> 4, n2 = (t >> 2) & 3, q2 = t & 3;
        float2 acc = covS[t];
        #pragma unroll
        for (int p = 0; p < 4; ++p)
          acc = cadd(acc, cmulc(Tb[(k2*4 + n2)*4 + p], Tb[(k2*4 + q2)*4 + p]));
        covS[t] = acc;
        if (k2 == j) HdVS[k2*16 + n2*4 + q2] = Tb[(k2*4 + n2)*4 + q2];
      }
      __syncthreads();
    }
  }

  // ============ phase B: per-user 4x4 chain -> uwS, Wall ============
  if (t < K_) {
    const int k = t;
    float2 a[4][4], ic[4][4], hv[4][4], u[4][4], wi[4][4], w[4][4], uw[4][4], W[4][4];
    const float rwk = rweights[b*K_ + k];
    for (int r = 0; r < 4; ++r)
      for (int c2 = 0; c2 < 4; ++c2) a[r][c2] = covS[k*16 + r*4 + c2];
    herm4_inv(a, ic);
    for (int r = 0; r < 4; ++r)
      for (int c2 = 0; c2 < 4; ++c2) hv[r][c2] = HdVS[k*16 + r*4 + c2];
    for (int n = 0; n < 4; ++n)
      for (int p = 0; p < 4; ++p) {
        float2 s = {0,0};
        for (int q = 0; q < 4; ++q) s = cadd(s, cmul(ic[n][q], hv[q][p]));
        u[n][p] = s;
      }
    for (int n = 0; n < 4; ++n)
      for (int p = 0; p < 4; ++p) {
        float2 s = make_float2((n == p) ? 1.f : 0.f, 0.f);
        for (int q = 0; q < 4; ++q) s = csub(s, cmulc(hv[q][p], u[q][n]));
        wi[n][p] = s;
      }
    herm4_inv(wi, w);
    for (int n = 0; n < 4; ++n)
      for (int q = 0; q < 4; ++q) {
        float2 s = {0,0};
        for (int p = 0; p < 4; ++p) s = cadd(s, cmul(u[n][p], w[p][q]));
        uw[n][q] = s;
      }
    for (int n = 0; n < 4; ++n)
      for (int r = 0; r < 4; ++r) {
        float2 s = {0,0};
        for (int q = 0; q < 4; ++q) s = cadd(s, cmulc(uw[n][q], u[r][q]));
        W[n][r] = make_float2(s.x * rwk, s.y * rwk);
      }
    for (int n = 0; n < 4; ++n)
      for (int r = n; r < 4; ++r) {
        float2 x1 = W[n][r], x2 = W[r][n];
        float2 hm = make_float2(0.5f*(x1.x + x2.x), 0.5f*(x1.y - x2.y));
        W[n][r] = hm; W[r][n] = make_float2(hm.x, -hm.y);
      }
    for (int idx = 0; idx < 16; ++idx) {
      uwS[k*16 + idx]  = uw[idx >> 2][idx & 3];
      Wall[k*16 + idx] = W[idx >> 2][idx & 3];
    }
  }
  __syncthreads();

  // ============ vt -> B registers; bracket hi = sqrt(tr/bss) ============
  float2 Bv[8][4];
  #pragma unroll
  for (int j = 0; j < 8; ++j)
    #pragma unroll
    for (int b4 = 0; b4 < 4; ++b4) Bv[j][b4] = make_float2(0.f, 0.f);
  float trp = 0.f;
  #pragma unroll
  for (int b4 = 0; b4 < 4; ++b4) {
    const int col = tp + 32*b4;
    const int slot = col >> 2, q = col & 3;
    if (slot < nc) {
      const int k = ulist[slot];
      const float rwk = rweights[b*K_ + k];
      const int hb = (c*K_ + k) * 512;
      #pragma unroll
      for (int j = 0; j < 8; ++j) {
        const int r = rbase + j;
        float2 acc = {0,0};
        #pragma unroll
        for (int n = 0; n < 4; ++n)
          acc = cadd(acc, cmulc(uwS[k*16 + n*4 + q],
                     make_float2(H_re[hb + n*128 + r], H_im[hb + n*128 + r])));
        acc.x *= rwk; acc.y *= rwk;
        Bv[j][b4] = acc;
        trp += acc.x*acc.x + acc.y*acc.y;
      }
    }
  }
  #pragma unroll
  for (int o = 32; o >= 1; o >>= 1) trp += __shfl_xor(trp, o, 64);
  if (lane == 0) red[wid] = trp;
  __syncthreads();
  float tr = 0.f;
  #pragma unroll
  for (int w8 = 0; w8 < 8; ++w8) tr += red[w8];
  const float inv_bss = 1.f / bss_pow[b*C_ + c];
  float hi = sqrtf(tr * inv_bss);
  float lo = 0.f;

  // ============ ul = sum_k H^H W_k H into A registers (8x4/thread) ============
  float2 Areg[8][4];
  #pragma unroll
  for (int j = 0; j < 8; ++j)
    #pragma unroll
    for (int cc = 0; cc < 4; ++cc) Areg[j][cc] = make_float2(0.f, 0.f);
  __syncthreads();
  for (int k = 0; k < K_; ++k) {
    const int hb = (c*K_ + k) * 512;
    Hs[(t >> 7)*130 + (t & 127)] = make_float2(H_re[hb + t], H_im[hb + t]);
    __syncthreads();
    {
      const int n = t >> 7, p = t & 127;
      float2 y = {0,0};
      #pragma unroll
      for (int o = 0; o < 4; ++o) y = cadd(y, cmul(Wall[k*16 + n*4 + o], Hs[o*130 + p]));
      Ys[n*130 + p] = y;
    }
    __syncthreads();
    #pragma unroll
    for (int n = 0; n < 4; ++n) {
      float2 h[8], y[4];
      #pragma unroll
      for (int a2 = 0; a2 < 8; a2 += 2) {
        const float4 h4 = *(const float4*)&Hs[n*130 + rbase + a2];
        h[a2] = make_float2(h4.x, h4.y); h[a2+1] = make_float2(h4.z, h4.w);
      }
      {
        const float4 y0 = *(const float4*)&Ys[n*130 + 4*tp];
        const float4 y1 = *(const float4*)&Ys[n*130 + 4*tp + 2];
        y[0] = make_float2(y0.x, y0.y); y[1] = make_float2(y0.z, y0.w);
        y[2] = make_float2(y1.x, y1.y); y[3] = make_float2(y1.z, y1.w);
      }
      #pragma unroll
      for (int j = 0; j < 8; ++j)
        #pragma unroll
        for (int cc = 0; cc < 4; ++cc) {   // A += conj(h)*y
          Areg[j][cc].x += h[j].x*y[cc].x + h[j].y*y[cc].y;
          Areg[j][cc].y += h[j].x*y[cc].y - h[j].y*y[cc].x;
        }
    }
    __syncthreads();
  }

  // ============ Householder tridiagonalization (127 steps, B fused) ============
  if (tp == 0) {
    #pragma unroll
    for (int j = 0; j < 8; ++j) colS[rbase + j] = Areg[j][0];
  }
  __syncthreads();

  for (int i = 0; i < 127; ++i) {
    // S1: wave0 generates reflector (zlarfg conventions, beta real)
    if (wid == 0) {
      const float2 x0 = colS[lane], x1 = colS[lane + 64];
      float sig = 0.f;
      if (lane >= i + 2)      sig += x0.x*x0.x + x0.y*x0.y;
      if (lane + 64 >= i + 2) sig += x1.x*x1.x + x1.y*x1.y;
      #pragma unroll
      for (int o = 32; o >= 1; o >>= 1) sig += __shfl_xor(sig, o, 64);
      const float2 al = colS[i + 1];
      float beta, taur = 0.f, taui = 0.f, scr = 0.f, sci = 0.f;
      if (sig <= 1e-30f && fabsf(al.y) <= 1e-30f) {
        beta = al.x;
      } else {
        const float mag = sqrtf(al.x*al.x + al.y*al.y + sig);
        beta = (al.x >= 0.f) ? -mag : mag;
        const float ib = 1.f / beta;
        taur = (beta - al.x) * ib; taui = -al.y * ib;
        const float dx = al.x - beta, dy = al.y;
        const float dn = 1.f / (dx*dx + dy*dy);
        scr = dx*dn; sci = -dy*dn;              // 1/(alpha-beta)
      }
      {
        float2 v0;
        if (lane <= i) v0 = make_float2(0.f, 0.f);
        else if (lane == i + 1) v0 = make_float2(1.f, 0.f);
        else v0 = make_float2(x0.x*scr - x0.y*sci, x0.x*sci + x0.y*scr);
        vS[lane] = v0;
        const int r1 = lane + 64;
        float2 v1;
        if (r1 <= i) v1 = make_float2(0.f, 0.f);
        else if (r1 == i + 1) v1 = make_float2(1.f, 0.f);
        else v1 = make_float2(x1.x*scr - x1.y*sci, x1.x*sci + x1.y*scr);
        vS[r1] = v1;
      }
      if (lane == 0) { eS[i] = beta; tauS[i] = make_float2(taur, taui); }
    }
    __syncthreads();

    // S2: matvec partials (shfl-reduced) + B-dot partials
    {
      float2 vc[4], vr[8];
      #pragma unroll
      for (int cc = 0; cc < 4; ++cc) vc[cc] = vS[4*tp + cc];
      #pragma unroll
      for (int j = 0; j < 8; ++j) vr[j] = vS[rbase + j];
      float2 part[8];
      #pragma unroll
      for (int j = 0; j < 8; ++j) {
        float2 s = cmul(Areg[j][0], vc[0]);
        s = cadd(s, cmul(Areg[j][1], vc[1]));
        s = cadd(s, cmul(Areg[j][2], vc[2]));
        s = cadd(s, cmul(Areg[j][3], vc[3]));
        part[j] = s;
      }
      #pragma unroll
      for (int o = 1; o <= 16; o <<= 1) {
        #pragma unroll
        for (int j = 0; j < 8; ++j) {
          part[j].x += __shfl_xor(part[j].x, o, 64);
          part[j].y += __shfl_xor(part[j].y, o, 64);
        }
      }
      #pragma unroll
      for (int j = 0; j < 8; ++j) if (tp == j) pvS[rbase + j] = part[j];
      #pragma unroll
      for (int b4 = 0; b4 < 4; ++b4) {
        float2 s = {0,0};
        #pragma unroll
        for (int j = 0; j < 8; ++j) s = cadd(s, cmulc(Bv[j][b4], vr[j]));  // conj(v)*B
        pS[tm*128 + tp + 32*b4] = s;
      }
    }
    __syncthreads();

    // S3: wave0 finishes w~ = tau*A*v + alpha*v
    if (wid == 0) {
      const float2 tau = tauS[i];
      float2 p0 = {0,0}, p1 = {0,0};
      if (lane > i)      p0 = cmul(tau, pvS[lane]);
      if (lane + 64 > i) p1 = cmul(tau, pvS[lane + 64]);
      float2 d0 = cadd(cmulc(p0, vS[lane]), cmulc(p1, vS[lane + 64]));  // v^H p
      #pragma unroll
      for (int o = 32; o >= 1; o >>= 1) {
        d0.x += __shfl_xor(d0.x, o, 64);
        d0.y += __shfl_xor(d0.y, o, 64);
      }
      const float alr = -0.5f * (tau.x*d0.x + tau.y*d0.y);  // -1/2 Re(conj(tau)*v^Hp)
      wS[lane]      = cadd(p0, make_float2(alr*vS[lane].x,      alr*vS[lane].y));
      wS[lane + 64] = cadd(p1, make_float2(alr*vS[lane+64].x,   alr*vS[lane+64].y));
    }
    __syncthreads();

    // S4: rank-2 update + B update + store v into col i + extract col i+1
    {
      float2 vr[8], wr[8], vc[4], wc[4];
      #pragma unroll
      for (int j = 0; j < 8; ++j) { vr[j] = vS[rbase + j]; wr[j] = wS[rbase + j]; }
      #pragma unroll
      for (int cc = 0; cc < 4; ++cc) { vc[cc] = vS[4*tp + cc]; wc[cc] = wS[4*tp + cc]; }
      #pragma unroll
      for (int j = 0; j < 8; ++j)
        #pragma unroll
        for (int cc = 0; cc < 4; ++cc)
          Areg[j][cc] = csub(Areg[j][cc], cadd(cmulc(vr[j], wc[cc]), cmulc(wr[j], vc[cc])));
      const float2 tau = tauS[i];
      const float2 tauc = make_float2(tau.x, -tau.y);
      #pragma unroll
      for (int b4 = 0; b4 < 4; ++b4) {
        float2 dB = {0,0};
        #pragma unroll
        for (int g = 0; g < 16; ++g) dB = cadd(dB, pS[g*128 + tp + 32*b4]);
        const float2 dBt = cmul(tauc, dB);
        #pragma unroll
        for (int j = 0; j < 8; ++j) Bv[j][b4] = csub(Bv[j][b4], cmul(dBt, vr[j]));
      }
      if (tp == (i >> 2)) {
        const int cc = i & 3;
        #pragma unroll
        for (int j = 0; j < 8; ++j) if (rbase + j >= i + 1) Areg[j][cc] = vr[j];
      }
      if (tp == ((i + 1) >> 2)) {
        const int cc = (i + 1) & 3;
        #pragma unroll
        for (int j = 0; j < 8; ++j) colS[rbase + j] = Areg[j][cc];
      }
    }
    __syncthreads();
  }

  // dump diagonal of T
  #pragma unroll
  for (int j = 0; j < 8; ++j) {
    const int r = rbase + j;
    if ((r >> 2) == tp) dS[r] = Areg[j][r & 3].x;
  }
  __syncthreads();

  // ============ bisection: 8 iters + final solve, Thomas on wave0 ============
  const int cols = 4 * nc;
  const int passes = (cols + 31) >> 5;
  for (int it = 0; it <= 8; ++it) {
    const float mu = 0.5f * (lo + hi);
    float fsum = 0.f;
    #pragma unroll
    for (int p = 0; p < 4; ++p) {
      if (p >= passes) continue;
      __syncthreads();
      #pragma unroll
      for (int j = 0; j < 8; ++j) Bs[(rbase + j)*32 + tp] = Bv[j][p];
      __syncthreads();
      if (wid == 0) {
        const int colg = 32*p + lane;
        const bool act = (lane < 32) && (colg < cols);
        float m = dS[0] + mu;
        float im = 1.f / m;
        float2 g = act ? Bs[lane] : make_float2(0.f, 0.f);
        g.x *= im; g.y *= im;
        if (act) Bs[lane] = g;
        float cp = eS[0] * im;
        if (lane == 0) cpS[0] = cp;
        for (int r = 1; r < 128; ++r) {
          const float e0 = eS[r-1];
          m = dS[r] + mu - e0 * cp;
          im = 1.f / m;
          float2 gr = act ? Bs[r*32 + lane] : make_float2(0.f, 0.f);
          gr.x = (gr.x - e0 * g.x) * im;
          gr.y = (gr.y - e0 * g.y) * im;
          g = gr;
          if (act) Bs[r*32 + lane] = gr;
          if (r < 127) { cp = eS[r] * im; if (lane == 0) cpS[r] = cp; }
        }
        float2 z = g;
        float acc = z.x*z.x + z.y*z.y;
        for (int r = 126; r >= 0; --r) {
          const float cpr = cpS[r];
          const float2 gp = act ? Bs[r*32 + lane] : make_float2(0.f, 0.f);
          z.x = gp.x - cpr * z.x;
          z.y = gp.y - cpr * z.y;
          acc += z.x*z.x + z.y*z.y;
          if (it == 8 && act) Bs[r*32 + lane] = z;
        }
        if (act) fsum += acc;
      }
      if (it == 8) {
        __syncthreads();
        #pragma unroll
        for (int j = 0; j < 8; ++j) Bv[j][p] = Bs[(rbase + j)*32 + tp];
      }
    }
    if (it < 8 && wid == 0) {
      #pragma unroll
      for (int o = 32; o >= 1; o >>= 1) fsum += __shfl_xor(fsum, o, 64);
      const float f = fsum * inv_bss;
      if (f > 1.0f) lo = mu; else hi = mu;
    }
  }
  __syncthreads();

  // ============ back-transform y = Q z (reverse reflector replay) ============
  for (int i = 126; i >= 0; --i) {
    if (t < 128 && t <= i) vS[t] = make_float2(0.f, 0.f);
    if (tp == (i >> 2)) {
      const int cc = i & 3;
      #pragma unroll
      for (int j = 0; j < 8; ++j) if (rbase + j >= i + 1) vS[rbase + j] = Areg[j][cc];
    }
    __syncthreads();
    float2 vr[8];
    #pragma unroll
    for (int j = 0; j < 8; ++j) vr[j] = vS[rbase + j];
    #pragma unroll
    for (int b4 = 0; b4 < 4; ++b4) {
      float2 s = {0,0};
      #pragma unroll
      for (int j = 0; j < 8; ++j) s = cadd(s, cmulc(Bv[j][b4], vr[j]));  // conj(v)*y
      pS[tm*128 + tp + 32*b4] = s;
    }
    __syncthreads();
    {
      const float2 tau = tauS[i];
      #pragma unroll
      for (int b4 = 0; b4 < 4; ++b4) {
        float2 dB = {0,0};
        #pragma unroll
        for (int g = 0; g < 16; ++g) dB = cadd(dB, pS[g*128 + tp + 32*b4]);
        const float2 dBt = cmul(tau, dB);
        #pragma unroll
        for (int j = 0; j < 8; ++j) Bv[j][b4] = csub(Bv[j][b4], cmul(dBt, vr[j]));
      }
    }
    __syncthreads();
  }

  // ============ output ============
  #pragma unroll
  for (int b4 = 0; b4 < 4; ++b4) {
    const int col = tp + 32*b4;
    const int slot = col >> 2, q = col & 3;
    if (slot < nc) {
      const int k = ulist[slot];
      const size_t base = (size_t)(b*K_ + k) * 512;
      #pragma unroll
      for (int j = 0; j < 8; ++j) {
        const size_t oe = base + (size_t)(rbase + j)*4 + q;
        if (omode == 0) ((float2*)outp)[oe] = Bv[j][b4];
        else            ((float*)outp)[oe]  = Bv[j][b4].x;
      }
    }
  }
}

// ======================================================================================
extern "C" void kernel_launch(void* const* d_in, const int* in_sizes, int n_in,
                              void* d_out, int out_size, void* d_ws, size_t ws_size,
                              hipStream_t stream)
{
  (void)in_sizes; (void)n_in; (void)d_ws; (void)ws_size;
  const float* v_re   = (const float*)d_in[0];
  const float* v_im   = (const float*)d_in[1];
  const float* H_re   = (const float*)d_in[2];
  const float* H_im   = (const float*)d_in[3];
  const float* noise  = (const float*)d_in[4];
  const float* rw     = (const float*)d_in[5];
  const float* bss    = (const float*)d_in[6];
  const int*   assign = (const int*)d_in[7];

  const int omode = (out_size == B_*K_*128*4) ? 1 : 0;  // real-only vs interleaved complex

  hipLaunchKernelGGL(k_fused, dim3(B_*C_), dim3(512), 0, stream,
                     v_re, v_im, H_re, H_im, noise, rw, bss, assign, d_out, omode);
}

// Round 9
// 1603.456 us; speedup vs baseline: 2.5389x; 2.3419x over previous
//
#include <hip/hip_runtime.h>

#define B_ 32
#define C_ 8
#define K_ 32

__device__ __forceinline__ float2 cmul(float2 a, float2 b) {
  return make_float2(a.x*b.x - a.y*b.y, a.x*b.y + a.y*b.x);
}
__device__ __forceinline__ float2 cmulc(float2 a, float2 b) { // a * conj(b)
  return make_float2(a.x*b.x + a.y*b.y, a.y*b.x - a.x*b.y);
}
__device__ __forceinline__ float2 cadd(float2 a, float2 b){ return make_float2(a.x+b.x, a.y+b.y); }
__device__ __forceinline__ float2 csub(float2 a, float2 b){ return make_float2(a.x-b.x, a.y-b.y); }

__device__ void herm4_inv(float2 a[4][4], float2 out[4][4]) {
  float idg[4];
  for (int j = 0; j < 4; ++j) {
    float d = sqrtf(fmaxf(a[j][j].x, 1e-30f));
    float id = 1.f / d;
    idg[j] = id;
    a[j][j] = make_float2(d, 0.f);
    for (int r = j+1; r < 4; ++r) { a[r][j].x *= id; a[r][j].y *= id; }
    for (int c = j+1; c < 4; ++c)
      for (int r = c; r < 4; ++r)
        a[r][c] = csub(a[r][c], cmulc(a[r][j], a[c][j]));
  }
  float2 li[4][4];
  for (int j = 0; j < 4; ++j) {
    li[j][j] = make_float2(idg[j], 0.f);
    for (int r = j+1; r < 4; ++r) {
      float2 s = make_float2(0.f, 0.f);
      for (int d = j; d < r; ++d) s = cadd(s, cmul(a[r][d], li[d][j]));
      li[r][j] = make_float2(-s.x*idg[r], -s.y*idg[r]);
    }
  }
  for (int p = 0; p < 4; ++p)
    for (int q = 0; q < 4; ++q) {
      float2 s = make_float2(0.f, 0.f);
      for (int d = (p > q ? p : q); d < 4; ++d)
        s = cadd(s, cmulc(li[d][q], li[d][p]));
      out[p][q] = s;
    }
}

// 256 threads, 1 block/CU. Thread (tm=t>>4, tp=t&15): A rows 8tm..8tm+7 x cols
// 8tp..8tp+7 (128 VGPRs); B rows 8tm..8tm+7 x cols tp+16q, q=0..7 (128 VGPRs).
// NO dynamic register indexing anywhere (unroll + compare guards).
__global__ __launch_bounds__(256, 1) void k_fused(
    const float* __restrict__ v_re, const float* __restrict__ v_im,
    const float* __restrict__ H_re, const float* __restrict__ H_im,
    const float* __restrict__ noise_pow, const float* __restrict__ rweights,
    const float* __restrict__ bss_pow, const int* __restrict__ assign_g,
    void* __restrict__ outp, int omode)
{
  const int t = threadIdx.x;
  const int lane = t & 63, wid = t >> 6;
  const int blk = blockIdx.x;
  const int b = blk >> 3, c = blk & 7;
  const int tm = t >> 4, tp = t & 15;
  const int rbase = tm * 8, cbase = tp * 8;

  __shared__ __align__(16) float2 Arena[4096];  // 32 KB: phaseA | Hs/Ys | Bs(128x32)
  __shared__ __align__(16) float2 pS[2048];     // 16 KB: Wall+uwS early; dot partials later
  __shared__ __align__(16) float2 dBS[128];
  __shared__ __align__(16) float2 vS[128];
  __shared__ __align__(16) float2 wS[128];
  __shared__ __align__(16) float2 colS[128];
  __shared__ __align__(16) float2 pvS[128];
  __shared__ __align__(16) float2 tauS[128];
  __shared__ float dS[128], eS[128], cpS[128];
  __shared__ float red[4];
  __shared__ int asg[K_], ulist[K_], nc_s;

  float2* Wall = pS;              // 512 (until end of ul phase)
  float2* uwS  = pS + 512;        // 512 (until end of vt phase)
  float2* Vs   = Arena;           // 768 (phase A)
  float2* Tb   = Arena + 768;     // 512
  float2* covS = Arena + 1280;    // 512
  float2* HdVS = Arena + 1792;    // 512
  float2* Hs   = Arena;           // 520 (ul phase)
  float2* Ys   = Arena + 520;     // 520
  float2* Bs   = Arena;           // 4096 (bisection, 128 x 32)

  if (t < K_) asg[t] = assign_g[t];
  if (t == 0) {
    int nc = 0;
    for (int k = 0; k < K_; ++k) if (assign_g[k] == c) ulist[nc++] = k;
    nc_s = nc;
  }
  #pragma unroll
  for (int s2 = 0; s2 < 2; ++s2) {   // cov := noise * I
    const int s = t + 256*s2;
    const int k = s >> 4, n = (s >> 2) & 3, q = s & 3;
    covS[s] = make_float2((n == q) ? noise_pow[b*K_ + k] : 0.f, 0.f);
  }
  __syncthreads();
  const int nc = nc_s;
  if (nc == 0) return;
  const int cols = 4 * nc;
  const int qmax = (cols + 15) >> 4;
  const int passes = (cols + 31) >> 5;

  // ============ phase A: T_{jk} = H[asg_j,k] @ V_j ; cov_k += T T^H ============
  {
    const int pn = t >> 1;           // (k,n): kk = pn>>2, nn = pn&3
    const int qt = t & 1;            // m half
    const int kk = pn >> 2, nn = pn & 3;
    for (int j = 0; j < K_; ++j) {
      const int vb = (b*K_ + j) * 512;
      #pragma unroll
      for (int s2 = 0; s2 < 2; ++s2) {
        const int s = t + 256*s2;
        Vs[(s >> 2)*6 + (s & 3)] = make_float2(v_re[vb + s], v_im[vb + s]);
      }
      __syncthreads();
      const int hb = ((asg[j]*K_ + kk)*4 + nn) * 128;
      float2 a0 = {0,0}, a1 = {0,0}, a2 = {0,0}, a3 = {0,0};
      for (int m4 = qt*64; m4 < qt*64 + 64; m4 += 4) {
        const float4 hre = *(const float4*)&H_re[hb + m4];
        const float4 him = *(const float4*)&H_im[hb + m4];
        const float hx[4] = {hre.x, hre.y, hre.z, hre.w};
        const float hy[4] = {him.x, him.y, him.z, him.w};
        #pragma unroll
        for (int i = 0; i < 4; ++i) {
          const float4 v01 = *(const float4*)&Vs[(m4 + i)*6];
          const float4 v23 = *(const float4*)&Vs[(m4 + i)*6 + 2];
          a0.x += hx[i]*v01.x - hy[i]*v01.y; a0.y += hx[i]*v01.y + hy[i]*v01.x;
          a1.x += hx[i]*v01.z - hy[i]*v01.w; a1.y += hx[i]*v01.w + hy[i]*v01.z;
          a2.x += hx[i]*v23.x - hy[i]*v23.y; a2.y += hx[i]*v23.y + hy[i]*v23.x;
          a3.x += hx[i]*v23.z - hy[i]*v23.w; a3.y += hx[i]*v23.w + hy[i]*v23.z;
        }
      }
      a0.x += __shfl_xor(a0.x, 1, 64); a0.y += __shfl_xor(a0.y, 1, 64);
      a1.x += __shfl_xor(a1.x, 1, 64); a1.y += __shfl_xor(a1.y, 1, 64);
      a2.x += __shfl_xor(a2.x, 1, 64); a2.y += __shfl_xor(a2.y, 1, 64);
      a3.x += __shfl_xor(a3.x, 1, 64); a3.y += __shfl_xor(a3.y, 1, 64);
      if (qt == 0) {
        Tb[pn*4 + 0] = a0; Tb[pn*4 + 1] = a1; Tb[pn*4 + 2] = a2; Tb[pn*4 + 3] = a3;
      }
      __syncthreads();
      #pragma unroll
      for (int s2 = 0; s2 < 2; ++s2) {
        const int s = t + 256*s2;
        const int k2 = s >> 4, n2 = (s >> 2) & 3, q2 = s & 3;
        float2 acc = covS[s];
        #pragma unroll
        for (int p = 0; p < 4; ++p)
          acc = cadd(acc, cmulc(Tb[(k2*4 + n2)*4 + p], Tb[(k2*4 + q2)*4 + p]));
        covS[s] = acc;
        if (k2 == j) HdVS[k2*16 + n2*4 + q2] = Tb[(k2*4 + n2)*4 + q2];
      }
      __syncthreads();
    }
  }

  // ============ phase B: per-user 4x4 chain -> uwS, Wall ============
  if (t < K_) {
    const int k = t;
    float2 a[4][4], ic[4][4], hv[4][4], u[4][4], wi[4][4], w[4][4], uw[4][4], W[4][4];
    const float rwk = rweights[b*K_ + k];
    for (int r = 0; r < 4; ++r)
      for (int c2 = 0; c2 < 4; ++c2) a[r][c2] = covS[k*16 + r*4 + c2];
    herm4_inv(a, ic);
    for (int r = 0; r < 4; ++r)
      for (int c2 = 0; c2 < 4; ++c2) hv[r][c2] = HdVS[k*16 + r*4 + c2];
    for (int n = 0; n < 4; ++n)
      for (int p = 0; p < 4; ++p) {
        float2 s = {0,0};
        for (int q = 0; q < 4; ++q) s = cadd(s, cmul(ic[n][q], hv[q][p]));
        u[n][p] = s;
      }
    for (int n = 0; n < 4; ++n)
      for (int p = 0; p < 4; ++p) {
        float2 s = make_float2((n == p) ? 1.f : 0.f, 0.f);
        for (int q = 0; q < 4; ++q) s = csub(s, cmulc(hv[q][p], u[q][n]));
        wi[n][p] = s;
      }
    herm4_inv(wi, w);
    for (int n = 0; n < 4; ++n)
      for (int q = 0; q < 4; ++q) {
        float2 s = {0,0};
        for (int p = 0; p < 4; ++p) s = cadd(s, cmul(u[n][p], w[p][q]));
        uw[n][q] = s;
      }
    for (int n = 0; n < 4; ++n)
      for (int r = 0; r < 4; ++r) {
        float2 s = {0,0};
        for (int q = 0; q < 4; ++q) s = cadd(s, cmulc(uw[n][q], u[r][q]));
        W[n][r] = make_float2(s.x * rwk, s.y * rwk);
      }
    for (int n = 0; n < 4; ++n)
      for (int r = n; r < 4; ++r) {
        float2 x1 = W[n][r], x2 = W[r][n];
        float2 hm = make_float2(0.5f*(x1.x + x2.x), 0.5f*(x1.y - x2.y));
        W[n][r] = hm; W[r][n] = make_float2(hm.x, -hm.y);
      }
    for (int idx = 0; idx < 16; ++idx) {
      uwS[k*16 + idx]  = uw[idx >> 2][idx & 3];
      Wall[k*16 + idx] = W[idx >> 2][idx & 3];
    }
  }
  __syncthreads();

  // ============ vt -> B registers (col tp+16q); bracket hi ============
  float2 Bv[8][8];
  #pragma unroll
  for (int j = 0; j < 8; ++j)
    #pragma unroll
    for (int q = 0; q < 8; ++q) Bv[j][q] = make_float2(0.f, 0.f);
  float trp = 0.f;
  #pragma unroll
  for (int q = 0; q < 8; ++q) {
    const int col = tp + 16*q;
    const int slot = col >> 2, qn = col & 3;
    if (slot < nc) {
      const int k = ulist[slot];
      const float rwk = rweights[b*K_ + k];
      const int hb = (c*K_ + k) * 512;
      #pragma unroll
      for (int j = 0; j < 8; ++j) {
        const int r = rbase + j;
        float2 acc = {0,0};
        #pragma unroll
        for (int n = 0; n < 4; ++n)
          acc = cadd(acc, cmulc(uwS[k*16 + n*4 + qn],
                     make_float2(H_re[hb + n*128 + r], H_im[hb + n*128 + r])));
        acc.x *= rwk; acc.y *= rwk;
        Bv[j][q] = acc;
        trp += acc.x*acc.x + acc.y*acc.y;
      }
    }
  }
  #pragma unroll
  for (int o = 32; o >= 1; o >>= 1) trp += __shfl_xor(trp, o, 64);
  if (lane == 0) red[wid] = trp;
  __syncthreads();
  const float inv_bss = 1.f / bss_pow[b*C_ + c];
  float hi = sqrtf((red[0] + red[1] + red[2] + red[3]) * inv_bss);
  float lo = 0.f;

  // ============ ul = sum_k H^H W_k H into A registers (8x8/thread) ============
  float2 Areg[8][8];
  #pragma unroll
  for (int j = 0; j < 8; ++j)
    #pragma unroll
    for (int cc = 0; cc < 8; ++cc) Areg[j][cc] = make_float2(0.f, 0.f);
  __syncthreads();
  for (int k = 0; k < K_; ++k) {
    const int hb = (c*K_ + k) * 512;
    #pragma unroll
    for (int s2 = 0; s2 < 2; ++s2) {
      const int s = t + 256*s2;
      Hs[(s >> 7)*130 + (s & 127)] = make_float2(H_re[hb + s], H_im[hb + s]);
    }
    __syncthreads();
    #pragma unroll
    for (int s2 = 0; s2 < 2; ++s2) {
      const int s = t + 256*s2;
      const int n = s >> 7, p = s & 127;
      float2 y = {0,0};
      #pragma unroll
      for (int o = 0; o < 4; ++o) y = cadd(y, cmul(Wall[k*16 + n*4 + o], Hs[o*130 + p]));
      Ys[n*130 + p] = y;
    }
    __syncthreads();
    #pragma unroll
    for (int n = 0; n < 4; ++n) {
      float2 h[8], y[8];
      #pragma unroll
      for (int a2 = 0; a2 < 8; a2 += 2) {
        const float4 h4 = *(const float4*)&Hs[n*130 + rbase + a2];
        h[a2] = make_float2(h4.x, h4.y); h[a2+1] = make_float2(h4.z, h4.w);
        const float4 y4 = *(const float4*)&Ys[n*130 + cbase + a2];
        y[a2] = make_float2(y4.x, y4.y); y[a2+1] = make_float2(y4.z, y4.w);
      }
      #pragma unroll
      for (int j = 0; j < 8; ++j)
        #pragma unroll
        for (int cc = 0; cc < 8; ++cc) {   // A += conj(h)*y
          Areg[j][cc].x += h[j].x*y[cc].x + h[j].y*y[cc].y;
          Areg[j][cc].y += h[j].x*y[cc].y - h[j].y*y[cc].x;
        }
    }
    __syncthreads();
  }

  // ============ Householder tridiagonalization (127 steps, B fused) ============
  if (tp == 0) {
    #pragma unroll
    for (int j = 0; j < 8; ++j) colS[rbase + j] = Areg[j][0];
  }
  __syncthreads();

  #pragma unroll 1
  for (int i = 0; i < 127; ++i) {
    // S1: wave0 generates reflector (zlarfg; beta real)
    if (wid == 0) {
      const float2 x0 = colS[lane], x1 = colS[lane + 64];
      float sig = 0.f;
      if (lane >= i + 2)      sig += x0.x*x0.x + x0.y*x0.y;
      if (lane + 64 >= i + 2) sig += x1.x*x1.x + x1.y*x1.y;
      #pragma unroll
      for (int o = 32; o >= 1; o >>= 1) sig += __shfl_xor(sig, o, 64);
      const float2 al = colS[i + 1];
      float beta, taur = 0.f, taui = 0.f, scr = 0.f, sci = 0.f;
      if (sig <= 1e-30f && fabsf(al.y) <= 1e-30f) {
        beta = al.x;
      } else {
        const float mag = sqrtf(al.x*al.x + al.y*al.y + sig);
        beta = (al.x >= 0.f) ? -mag : mag;
        const float ib = 1.f / beta;
        taur = (beta - al.x) * ib; taui = -al.y * ib;
        const float dx = al.x - beta, dy = al.y;
        const float dn = 1.f / (dx*dx + dy*dy);
        scr = dx*dn; sci = -dy*dn;
      }
      {
        float2 v0;
        if (lane <= i) v0 = make_float2(0.f, 0.f);
        else if (lane == i + 1) v0 = make_float2(1.f, 0.f);
        else v0 = make_float2(x0.x*scr - x0.y*sci, x0.x*sci + x0.y*scr);
        vS[lane] = v0;
        const int r1 = lane + 64;
        float2 v1;
        if (r1 <= i) v1 = make_float2(0.f, 0.f);
        else if (r1 == i + 1) v1 = make_float2(1.f, 0.f);
        else v1 = make_float2(x1.x*scr - x1.y*sci, x1.x*sci + x1.y*scr);
        vS[r1] = v1;
      }
      if (lane == 0) { eS[i] = beta; tauS[i] = make_float2(taur, taui); }
    }
    __syncthreads();

    // S2: matvec partials + B-dot partials
    float2 vr[8], vc[8];
    #pragma unroll
    for (int j = 0; j < 8; ++j) vr[j] = vS[rbase + j];
    #pragma unroll
    for (int cc = 0; cc < 8; ++cc) vc[cc] = vS[cbase + cc];
    {
      float2 part[8];
      #pragma unroll
      for (int j = 0; j < 8; ++j) {
        float2 s = cmul(Areg[j][0], vc[0]);
        #pragma unroll
        for (int cc = 1; cc < 8; ++cc) s = cadd(s, cmul(Areg[j][cc], vc[cc]));
        part[j] = s;
      }
      #pragma unroll
      for (int o = 1; o <= 8; o <<= 1) {
        #pragma unroll
        for (int j = 0; j < 8; ++j) {
          part[j].x += __shfl_xor(part[j].x, o, 64);
          part[j].y += __shfl_xor(part[j].y, o, 64);
        }
      }
      #pragma unroll
      for (int j = 0; j < 8; ++j) if (tp == j) pvS[rbase + j] = part[j];
      #pragma unroll
      for (int q = 0; q < 8; ++q) {
        if (q >= qmax) continue;
        float2 s = {0,0};
        #pragma unroll
        for (int j = 0; j < 8; ++j) s = cadd(s, cmulc(Bv[j][q], vr[j]));  // conj(v)*B
        pS[tm*128 + tp + 16*q] = s;
      }
    }
    __syncthreads();

    // S3: wave0 builds w~ ; waves1-2 reduce B-dots
    if (wid == 0) {
      const float2 tau = tauS[i];
      float2 p0 = {0,0}, p1 = {0,0};
      if (lane > i)      p0 = cmul(tau, pvS[lane]);
      if (lane + 64 > i) p1 = cmul(tau, pvS[lane + 64]);
      float2 d0 = cadd(cmulc(p0, vS[lane]), cmulc(p1, vS[lane + 64]));
      #pragma unroll
      for (int o = 32; o >= 1; o >>= 1) {
        d0.x += __shfl_xor(d0.x, o, 64);
        d0.y += __shfl_xor(d0.y, o, 64);
      }
      const float alr = -0.5f * (tau.x*d0.x + tau.y*d0.y);
      wS[lane]      = cadd(p0, make_float2(alr*vS[lane].x,    alr*vS[lane].y));
      wS[lane + 64] = cadd(p1, make_float2(alr*vS[lane+64].x, alr*vS[lane+64].y));
    } else if (t < 192) {
      const int col = t - 64;
      float2 s = {0,0};
      #pragma unroll
      for (int g = 0; g < 16; ++g) s = cadd(s, pS[g*128 + col]);
      dBS[col] = s;
    }
    __syncthreads();

    // S4: rank-2 update + B update + store v col i + extract col i+1
    {
      float2 wr[8], wc[8];
      #pragma unroll
      for (int j = 0; j < 8; ++j) wr[j] = wS[rbase + j];
      #pragma unroll
      for (int cc = 0; cc < 8; ++cc) wc[cc] = wS[cbase + cc];
      #pragma unroll
      for (int j = 0; j < 8; ++j)
        #pragma unroll
        for (int cc = 0; cc < 8; ++cc)   // BUGFIX: A[r][c] -= v[r]*conj(w[c]) + w[r]*conj(v[c])
          Areg[j][cc] = csub(Areg[j][cc], cadd(cmulc(vr[j], wc[cc]), cmulc(wr[j], vc[cc])));
      const float2 tau = tauS[i];
      const float2 tauc = make_float2(tau.x, -tau.y);
      #pragma unroll
      for (int q = 0; q < 8; ++q) {
        if (q >= qmax) continue;
        const float2 dBt = cmul(tauc, dBS[tp + 16*q]);
        #pragma unroll
        for (int j = 0; j < 8; ++j) Bv[j][q] = csub(Bv[j][q], cmul(dBt, vr[j]));
      }
      if (tp == (i >> 3)) {
        #pragma unroll
        for (int cc = 0; cc < 8; ++cc) if (cc == (i & 7)) {
          #pragma unroll
          for (int j = 0; j < 8; ++j) if (rbase + j >= i + 1) Areg[j][cc] = vr[j];
        }
      }
      if (tp == ((i + 1) >> 3)) {
        #pragma unroll
        for (int cc = 0; cc < 8; ++cc) if (cc == ((i + 1) & 7)) {
          #pragma unroll
          for (int j = 0; j < 8; ++j) colS[rbase + j] = Areg[j][cc];
        }
      }
    }
    __syncthreads();
  }

  // diag of T (row rbase+j lives in col-owner tp == tm)
  if (tp == tm) {
    #pragma unroll
    for (int j = 0; j < 8; ++j) dS[rbase + j] = Areg[j][j].x;
  }
  __syncthreads();

  // ============ bisection: 8 iters + final solve (Thomas, wave0) ============
  for (int it = 0; it <= 8; ++it) {
    const float mu = 0.5f * (lo + hi);
    float fsum = 0.f;
    #pragma unroll
    for (int p = 0; p < 4; ++p) {
      if (p >= passes) continue;
      __syncthreads();
      #pragma unroll
      for (int j = 0; j < 8; ++j) {
        Bs[(rbase + j)*32 + tp]      = Bv[j][2*p];
        Bs[(rbase + j)*32 + tp + 16] = Bv[j][2*p + 1];
      }
      __syncthreads();
      if (wid == 0) {
        const int colg = 32*p + lane;
        const bool act = (lane < 32) && (colg < cols);
        float m = dS[0] + mu;
        float im = 1.f / m;
        float2 g = act ? Bs[lane] : make_float2(0.f, 0.f);
        g.x *= im; g.y *= im;
        if (act) Bs[lane] = g;
        float cp = eS[0] * im;
        if (lane == 0) cpS[0] = cp;
        for (int r = 1; r < 128; ++r) {
          const float e0 = eS[r-1];
          m = dS[r] + mu - e0 * cp;
          im = 1.f / m;
          float2 gr = act ? Bs[r*32 + lane] : make_float2(0.f, 0.f);
          gr.x = (gr.x - e0 * g.x) * im;
          gr.y = (gr.y - e0 * g.y) * im;
          g = gr;
          if (act) Bs[r*32 + lane] = gr;
          if (r < 127) { cp = eS[r] * im; if (lane == 0) cpS[r] = cp; }
        }
        float2 z = g;
        float acc = z.x*z.x + z.y*z.y;
        for (int r = 126; r >= 0; --r) {
          const float cpr = cpS[r];
          const float2 gp = act ? Bs[r*32 + lane] : make_float2(0.f, 0.f);
          z.x = gp.x - cpr * z.x;
          z.y = gp.y - cpr * z.y;
          acc += z.x*z.x + z.y*z.y;
          if (it == 8 && act) Bs[r*32 + lane] = z;
        }
        if (act) fsum += acc;
      }
      if (it == 8) {
        __syncthreads();
        #pragma unroll
        for (int j = 0; j < 8; ++j) {
          Bv[j][2*p]     = Bs[(rbase + j)*32 + tp];
          Bv[j][2*p + 1] = Bs[(rbase + j)*32 + tp + 16];
        }
      }
    }
    if (it < 8 && wid == 0) {
      #pragma unroll
      for (int o = 32; o >= 1; o >>= 1) fsum += __shfl_xor(fsum, o, 64);
      const float f = fsum * inv_bss;
      if (f > 1.0f) lo = mu; else hi = mu;   // only wave0's lo/hi are consumed
    }
  }
  __syncthreads();

  // ============ back-transform y = Q z (reverse reflector replay) ============
  #pragma unroll 1
  for (int i = 126; i >= 0; --i) {
    if (t < 128 && t <= i) vS[t] = make_float2(0.f, 0.f);
    if (tp == (i >> 3)) {
      #pragma unroll
      for (int cc = 0; cc < 8; ++cc) if (cc == (i & 7)) {
        #pragma unroll
        for (int j = 0; j < 8; ++j) if (rbase + j >= i + 1) vS[rbase + j] = Areg[j][cc];
      }
    }
    __syncthreads();
    float2 vr[8];
    #pragma unroll
    for (int j = 0; j < 8; ++j) vr[j] = vS[rbase + j];
    #pragma unroll
    for (int q = 0; q < 8; ++q) {
      if (q >= qmax) continue;
      float2 s = {0,0};
      #pragma unroll
      for (int j = 0; j < 8; ++j) s = cadd(s, cmulc(Bv[j][q], vr[j]));
      pS[tm*128 + tp + 16*q] = s;
    }
    __syncthreads();
    if (t < 128) {
      float2 s = {0,0};
      #pragma unroll
      for (int g = 0; g < 16; ++g) s = cadd(s, pS[g*128 + t]);
      dBS[t] = s;
    }
    __syncthreads();
    {
      const float2 tau = tauS[i];
      #pragma unroll
      for (int q = 0; q < 8; ++q) {
        if (q >= qmax) continue;
        const float2 dBt = cmul(tau, dBS[tp + 16*q]);
        #pragma unroll
        for (int j = 0; j < 8; ++j) Bv[j][q] = csub(Bv[j][q], cmul(dBt, vr[j]));
      }
    }
    __syncthreads();
  }

  // ============ output ============
  #pragma unroll
  for (int q = 0; q < 8; ++q) {
    const int col = tp + 16*q;
    const int slot = col >> 2, qn = col & 3;
    if (slot < nc) {
      const int k = ulist[slot];
      const size_t base = (size_t)(b*K_ + k) * 512;
      #pragma unroll
      for (int j = 0; j < 8; ++j) {
        const size_t oe = base + (size_t)(rbase + j)*4 + qn;
        if (omode == 0) ((float2*)outp)[oe] = Bv[j][q];
        else            ((float*)outp)[oe]  = Bv[j][q].x;
      }
    }
  }
}

// ======================================================================================
extern "C" void kernel_launch(void* const* d_in, const int* in_sizes, int n_in,
                              void* d_out, int out_size, void* d_ws, size_t ws_size,
                              hipStream_t stream)
{
  (void)in_sizes; (void)n_in; (void)d_ws; (void)ws_size;
  const float* v_re   = (const float*)d_in[0];
  const float* v_im   = (const float*)d_in[1];
  const float* H_re   = (const float*)d_in[2];
  const float* H_im   = (const float*)d_in[3];
  const float* noise  = (const float*)d_in[4];
  const float* rw     = (const float*)d_in[5];
  const float* bss    = (const float*)d_in[6];
  const int*   assign = (const int*)d_in[7];

  const int omode = (out_size == B_*K_*128*4) ? 1 : 0;  // real-only vs interleaved complex

  hipLaunchKernelGGL(k_fused, dim3(B_*C_), dim3(256), 0, stream,
                     v_re, v_im, H_re, H_im, noise, rw, bss, assign, d_out, omode);
}